// Round 9
// baseline (656.950 us; speedup 1.0000x reference)
//
#include <hip/hip_runtime.h>
#include <math.h>

#define NW   5
#define PRJ  14
#define CCH  512
#define PP   100
#define NQ   375
#define NS   70
#define NPAIR (NQ*NW)

// ws offsets (floats)
#define OFF_PROTO   0          // 5*512*100 = 256000
#define OFF_PAVG    256000     // 2560
#define OFF_QAVG    258560     // 192000
#define OFF_QSQ     450560     // 37500
#define OFF_PSQ     488060     // 500
#define OFF_LOGITS  488560     // 1875
#define OFF_PF16    490440     // 5 protos * 16 kt * 2048 dwords = 163840

typedef float f32x16 __attribute__((ext_vector_type(16)));
typedef _Float16 f16x2 __attribute__((ext_vector_type(2)));
typedef _Float16 f16x8 __attribute__((ext_vector_type(8)));

__device__ __forceinline__ int SWZ(int n) { return n ^ ((n >> 2) & 7); }

// ---------------- K1: proto = mean over shots; proto_avg ----------------
__global__ void k_proto(const float* __restrict__ feat, float* __restrict__ ws) {
    int nc = blockIdx.x;            // n*512 + c
    int n  = nc >> 9;
    int p  = threadIdx.x;
    float s = 0.f;
    if (p < PP) {
        const float* base = feat + (size_t)((n * PRJ) * CCH) * PP + (size_t)(nc & 511) * PP + p;
        #pragma unroll
        for (int k = 0; k < PRJ; ++k) s += base[(size_t)k * CCH * PP];
        s *= (1.f / PRJ);
        ws[OFF_PROTO + nc * PP + p] = s;
    }
    float v = (p < PP) ? s : 0.f;
    #pragma unroll
    for (int off = 32; off; off >>= 1) v += __shfl_down(v, off);
    __shared__ float red[2];
    if ((threadIdx.x & 63) == 0) red[threadIdx.x >> 6] = v;
    __syncthreads();
    if (threadIdx.x == 0) ws[OFF_PAVG + nc] = (red[0] + red[1]) * (1.f / PP);
}

// ------- K2: per-image transpose-stats: sumsq per node (+ optional avg per ch)
__global__ __launch_bounds__(256) void k_qstat(const float* __restrict__ src,
                                               float* __restrict__ dst_sq,
                                               float* __restrict__ dst_avg) {
    __shared__ __align__(16) float t[6400];
    int b = blockIdx.x, tid = threadIdx.x;
    const float* base = src + (size_t)b * CCH * PP;
    float qsq = 0.f;
    for (int c0 = 0; c0 < CCH; c0 += 64) {
        __syncthreads();
        const float4* g = (const float4*)(base + (size_t)c0 * PP);
        for (int i = tid; i < 1600; i += 256) ((float4*)t)[i] = g[i];
        __syncthreads();
        if (tid < PP) {
            #pragma unroll 8
            for (int c = 0; c < 64; ++c) { float x = t[c * PP + tid]; qsq = fmaf(x, x, qsq); }
        } else if (tid >= 128 && tid < 192) {
            int ch = tid - 128;
            const float4* row = (const float4*)(t + ch * PP);
            float s = 0.f;
            #pragma unroll
            for (int i = 0; i < 25; ++i) { float4 v = row[i]; s += (v.x + v.y) + (v.z + v.w); }
            if (dst_avg) dst_avg[(size_t)b * CCH + c0 + ch] = s * (1.f / PP);
        }
    }
    if (tid < PP) dst_sq[b * PP + tid] = qsq;
}

// ------- K2b: pre-convert protos to SWZ'd f16 images (8KB per kt) -------
// logical col 100 = pavg (phys slot 101), col 101 = ones (phys slot 100)
__global__ __launch_bounds__(256) void k_pconv(float* __restrict__ ws) {
    int b = blockIdx.x;          // n*16 + kt
    int n = b >> 4, kt = b & 15;
    int tid = threadIdx.x;
    int c0 = kt * 32;
    uint* img = (uint*)(ws + OFF_PF16) + (size_t)b * 2048;
    const float* pb = ws + OFF_PROTO + (size_t)n * CCH * PP;
    const float* pavg = ws + OFF_PAVG + n * CCH;
    for (int i = tid; i < 1600; i += 256) {
        int cp = i / 100, col = i - cp * 100;
        float a0 = pb[(size_t)(c0 + 2 * cp) * PP + col];
        float a1 = pb[(size_t)(c0 + 2 * cp + 1) * PP + col];
        uint pk = __builtin_bit_cast(uint, __builtin_amdgcn_cvt_pkrtz(a0, a1));
        img[(((cp >> 2) << 7) | SWZ(col)) * 4 + (cp & 3)] = pk;
    }
    if (tid < 16) {
        int cp = tid;
        float a0 = pavg[c0 + 2 * cp], a1 = pavg[c0 + 2 * cp + 1];
        uint pk = __builtin_bit_cast(uint, __builtin_amdgcn_cvt_pkrtz(a0, a1));
        img[(((cp >> 2) << 7) | 101) * 4 + (cp & 3)] = pk;
    }
    for (int i = tid; i < 448; i += 256) {
        int dw = i & 3; int t2 = i >> 2;
        int s_i = t2 % 28; int k4 = t2 / 28;   // k4 0..3
        int s = 100 + s_i;
        if (s == 101) continue;
        img[(((k4) << 7) | s) * 4 + dw] = (s == 100) ? 0x3C003C00u : 0u;
    }
}

// ------- K3: per-pair: f16 MFMA cost matmul + weights + reg Sinkhorn ----
__global__ __launch_bounds__(256, 5) void k_pair(const float* __restrict__ query,
                                                 float* __restrict__ ws) {
    // SH union: matmul tiles A@0 (8KB), B@8192 (8KB) -> Gibbs Kst (22400B)
    __shared__ __align__(16) char SH[22400];
    __shared__ __align__(16) float uvec[112], vvec[112];   // halves at [0,50) and [56,106)
    __shared__ float wrL[PP], wcL[PP], qnl[PP], pnl[PP], sqv[PP], spv[PP];
    __shared__ float red[8];

    uint* Kst = (uint*)SH;

    // bijective XCD swizzle (nwg=1875 = 8*234+3): same-query pairs land on one XCD
    int p_ = blockIdx.x;
    int xcd = p_ & 7, off_ = p_ >> 3;
    int pair = (xcd < 3) ? (xcd * 235 + off_) : (705 + (xcd - 3) * 234 + off_);

    int m = pair / NW;
    int n = pair - m * NW;
    int tid = threadIdx.x;
    int lane = tid & 63, wid = tid >> 6;
    int lrow = lane & 31, lhi = lane >> 5;

    const float* qb = query + (size_t)m * CCH * PP;
    const float* qavg_g = ws + OFF_QAVG + (size_t)m * CCH;
    const uint* pimg = (const uint*)(ws + OFF_PF16) + (size_t)n * 16 * 2048;

    // A pad slots once: phys slot 100 = ones (logical row 101), 102..127 = 0
    // (phys slot 101 = logical row 100 = qavg, rewritten per kt)
    for (int idx = tid; idx < 112; idx += 256) {
        int s_i = idx % 28; int k4 = idx / 28;
        int s = 100 + s_i;
        if (s == 101) continue;
        uint4 val = (s == 100)
                  ? make_uint4(0x3C003C00u, 0x3C003C00u, 0x3C003C00u, 0x3C003C00u)
                  : make_uint4(0u, 0u, 0u, 0u);
        *(uint4*)&SH[(k4 * 128 + s) * 16] = val;
    }

    f32x16 acc[4];
    #pragma unroll
    for (int tc = 0; tc < 4; ++tc)
        #pragma unroll
        for (int e = 0; e < 16; ++e) acc[tc][e] = 0.f;

    int arow16 = SWZ(32 * wid + lrow) * 16;
    int bcol16[4];
    #pragma unroll
    for (int tc = 0; tc < 4; ++tc) bcol16[tc] = SWZ(32 * tc + lrow) * 16;

    for (int kt = 0; kt < 16; ++kt) {
        int c0 = kt * 32;
        // A: query f32 -> f16 pairs, SWZ slots
        for (int idx = tid; idx < 400; idx += 256) {
            int cp = idx / 25, n4 = idx - cp * 25;
            const float* src = qb + (size_t)(c0 + 2 * cp) * PP + n4 * 4;
            float4 x0 = *(const float4*)src;
            float4 x1 = *(const float4*)(src + PP);
            const float* p0 = (const float*)&x0;
            const float* p1 = (const float*)&x1;
            int basedw = ((cp >> 2) << 7);
            int dwb = (cp & 3) * 4;
            #pragma unroll
            for (int i4 = 0; i4 < 4; ++i4) {
                int node = n4 * 4 + i4;
                uint pk = __builtin_bit_cast(uint, __builtin_amdgcn_cvt_pkrtz(p0[i4], p1[i4]));
                *(uint*)&SH[(basedw + SWZ(node)) * 16 + dwb] = pk;
            }
        }
        // A logical row 100 = qavg (phys slot 101)
        if (tid < 16) {
            int cp = tid;
            uint pk = __builtin_bit_cast(uint,
                __builtin_amdgcn_cvt_pkrtz(qavg_g[c0 + 2 * cp], qavg_g[c0 + 2 * cp + 1]));
            *(uint*)&SH[(((cp >> 2) << 7) + 101) * 16 + (cp & 3) * 4] = pk;
        }
        // B: copy pre-converted f16 proto image (8KB)
        {
            const float4* gB = (const float4*)(pimg + (size_t)kt * 2048);
            float4* sB = (float4*)&SH[8192];
            for (int i = tid; i < 512; i += 256) sB[i] = gB[i];
        }
        __syncthreads();
        __builtin_amdgcn_s_setprio(1);
        #pragma unroll
        for (int s = 0; s < 2; ++s) {
            int kb = (2 * s + lhi) * 2048;
            f16x8 ah = *(const f16x8*)&SH[kb + arow16];
            #pragma unroll
            for (int tc = 0; tc < 4; ++tc) {
                f16x8 bh = *(const f16x8*)&SH[8192 + kb + bcol16[tc]];
                acc[tc] = __builtin_amdgcn_mfma_f32_32x32x16_f16(ah, bh, acc[tc], 0, 0, 0);
            }
        }
        __builtin_amdgcn_s_setprio(0);
        __syncthreads();
    }

    // extract w1 (col 100), sum_q (col 101), w2 (row 100), sum_p (row 101)
    if ((lane & 31) == 4 || (lane & 31) == 5) {
        float* dst = ((lane & 31) == 4) ? wrL : sqv;
        #pragma unroll
        for (int reg = 0; reg < 16; ++reg) {
            int row = 32 * wid + (reg & 3) + 8 * (reg >> 2) + 4 * lhi;
            if (row < PP) dst[row] = acc[3][reg];
        }
    }
    if (wid == 3 && lhi == 1) {
        #pragma unroll
        for (int tc = 0; tc < 4; ++tc) {
            int col = 32 * tc + lrow;
            if (col < PP) { wcL[col] = acc[tc][0]; spv[col] = acc[tc][1]; }
        }
    }
    if (tid < 112) vvec[tid] = 1.f;
    __syncthreads();

    // normalize weights (prescaled by 2^15 to fold the f16 K scaling)
    float v1 = 0.f, v2 = 0.f;
    if (tid < PP) {
        v1 = fmaxf(wrL[tid], 0.f) + 0.00101f;
        v2 = fmaxf(wcL[tid], 0.f) + 0.00101f;
    }
    float s1 = v1, s2 = v2;
    #pragma unroll
    for (int off = 32; off; off >>= 1) { s1 += __shfl_down(s1, off); s2 += __shfl_down(s2, off); }
    if ((tid & 63) == 0) { red[tid >> 6] = s1; red[4 + (tid >> 6)] = s2; }
    __syncthreads();
    float t1 = red[0] + red[1], t2 = red[4] + red[5];
    if (tid < PP) {
        wrL[tid] = v1 * (100.f / t1) * 32768.f;
        wcL[tid] = v2 * (100.f / t2) * 32768.f;
        float sq = sqv[tid], sp = spv[tid];
        qnl[tid] = ws[OFF_QSQ + m * PP + tid] - sq * sq * (1.f / 512.f);
        pnl[tid] = ws[OFF_PSQ + n * PP + tid] - sp * sp * (1.f / 512.f);
    }
    __syncthreads();

    // sqd into acc; block max
    float spc[4], pnc[4];
    #pragma unroll
    for (int tc = 0; tc < 4; ++tc) {
        int col = 32 * tc + lrow;
        bool cv = col < PP;
        spc[tc] = cv ? spv[col] : 0.f;
        pnc[tc] = cv ? pnl[col] : 0.f;
    }
    float mymax = -1e30f;
    #pragma unroll
    for (int reg = 0; reg < 16; ++reg) {
        int row = 32 * wid + (reg & 3) + 8 * (reg >> 2) + 4 * lhi;
        bool rv = row < PP;
        float sqr = rv ? sqv[row] : 0.f;
        float qnr = rv ? qnl[row] : 0.f;
        #pragma unroll
        for (int tc = 0; tc < 4; ++tc) {
            float sqd = qnr + pnc[tc] - 2.f * (acc[tc][reg] - sqr * spc[tc] * (1.f / 512.f));
            acc[tc][reg] = sqd;
            int col = 32 * tc + lrow;
            if (rv && col < PP) mymax = fmaxf(mymax, sqd);
        }
    }
    #pragma unroll
    for (int off = 32; off; off >>= 1) mymax = fmaxf(mymax, __shfl_down(mymax, off));
    __syncthreads();
    if (lane == 0) red[wid] = mymax;
    __syncthreads();
    float scale = fmaxf(fmaxf(red[0], red[1]), fmaxf(red[2], red[3])) + 1e-6f;
    float k2 = (1.f / scale) * (20.f * 1.44269504088896f);

    // Gibbs K' = 2^(15 - sqd*k2) f16-pair rows -> Kst (tiles are dead)
    #pragma unroll
    for (int tc = 0; tc < 4; ++tc) {
        float kv[16];
        #pragma unroll
        for (int reg = 0; reg < 16; ++reg) kv[reg] = exp2f(fmaf(-acc[tc][reg], k2, 15.f));
        int col = 32 * tc + lrow;
        #pragma unroll
        for (int reg = 0; reg < 16; ++reg) {
            float pv = __shfl_xor(kv[reg], 1);
            int row = 32 * wid + (reg & 3) + 8 * (reg >> 2) + 4 * lhi;
            if (!(lane & 1) && row < PP && col < PP) {
                int j = col >> 1;
                int dw = (j < 25) ? j : (j + 3);     // halves at +0 / +28
                uint pk = __builtin_bit_cast(uint, __builtin_amdgcn_cvt_pkrtz(kv[reg], pv));
                Kst[row * 56 + dw] = pk;
            }
        }
    }
    __syncthreads();

    // load K row-half and gathered col-half into registers
    int r_ = tid >> 1, hf = tid & 1;
    bool sact = tid < 200;
    int widx = r_ + (r_ >= 50 ? 6 : 0);
    uint Kr[25], KTr[25];
    float wr_own = 0.f, wc_own = 0.f;
    if (sact) {
        const uint* rp = Kst + r_ * 56 + 28 * hf;
        #pragma unroll
        for (int q = 0; q < 25; ++q) Kr[q] = rp[q];
        int j = r_ >> 1;
        int dwc = (j < 25) ? j : (j + 3);
        int sh = (r_ & 1) * 16;
        const uint* cp0 = Kst + (50 * hf) * 56 + dwc;
        #pragma unroll
        for (int q = 0; q < 25; ++q) {
            uint d0 = cp0[(2 * q) * 56];
            uint d1 = cp0[(2 * q + 1) * 56];
            KTr[q] = ((d0 >> sh) & 0xFFFFu) | (((d1 >> sh) & 0xFFFFu) << 16);
        }
        wr_own = wrL[r_];
        wc_own = wcL[r_];
    }
    __syncthreads();

    // linear Sinkhorn, K in registers; only u/v broadcasts touch LDS
    for (int it = 0; it < 50; ++it) {
        if (sact) {
            const float* vp = vvec + hf * 56;
            float sA = 0.f, sB = 0.f;
            #pragma unroll
            for (int q = 0; q < 25; ++q) {
                f16x2 h = __builtin_bit_cast(f16x2, Kr[q]);
                sA = fmaf((float)h[0], vp[2 * q], sA);
                sB = fmaf((float)h[1], vp[2 * q + 1], sB);
            }
            float s = sA + sB;
            s += __shfl_xor(s, 1);
            if (!hf) uvec[widx] = wr_own * __builtin_amdgcn_rcpf(s);
        }
        __syncthreads();
        if (sact) {
            const float* up = uvec + hf * 56;
            float sA = 0.f, sB = 0.f;
            #pragma unroll
            for (int q = 0; q < 25; ++q) {
                f16x2 h = __builtin_bit_cast(f16x2, KTr[q]);
                sA = fmaf((float)h[0], up[2 * q], sA);
                sB = fmaf((float)h[1], up[2 * q + 1], sB);
            }
            float s = sA + sB;
            s += __shfl_xor(s, 1);
            if (!hf) vvec[widx] = wc_own * __builtin_amdgcn_rcpf(s);
        }
        __syncthreads();
    }

    // epilogue: sqd recovered from stored K'
    float lsum = 0.f;
    if (sact) {
        float ur = uvec[widx];
        const float* vp = vvec + hf * 56;
        float rk2 = scale * (1.f / (20.f * 1.44269504088896f));
        #pragma unroll
        for (int q = 0; q < 25; ++q) {
            f16x2 h = __builtin_bit_cast(f16x2, Kr[q]);
            float k0 = (float)h[0], k1 = (float)h[1];
            float sq0 = (15.f - __log2f(k0)) * rk2;
            float sq1 = (15.f - __log2f(k1)) * rk2;
            lsum = fmaf((1.f - sq0) * k0, vp[2 * q], lsum);
            lsum = fmaf((1.f - sq1) * k1, vp[2 * q + 1], lsum);
        }
        lsum *= ur;
    }
    #pragma unroll
    for (int off = 32; off; off >>= 1) lsum += __shfl_down(lsum, off);
    if (lane == 0) red[wid] = lsum;
    __syncthreads();
    if (tid == 0)
        ws[OFF_LOGITS + pair] = ((red[0] + red[1]) + (red[2] + red[3])) * (0.125f / 32768.f);
}

// ---------------- K4: log-softmax + loss --------------------------------
__global__ void k_final(const int* __restrict__ label, const float* __restrict__ ws,
                        float* __restrict__ out) {
    int t = threadIdx.x;   // 384 threads
    float contrib = 0.f;
    if (t < NQ) {
        float lg[NW];
        #pragma unroll
        for (int n = 0; n < NW; ++n) lg[n] = ws[OFF_LOGITS + t * NW + n];
        float mx = lg[0];
        #pragma unroll
        for (int n = 1; n < NW; ++n) mx = fmaxf(mx, lg[n]);
        float s = 0.f;
        #pragma unroll
        for (int n = 0; n < NW; ++n) s += expf(lg[n] - mx);
        float lse = mx + logf(s);
        int lab = label[t];
        #pragma unroll
        for (int n = 0; n < NW; ++n) {
            float lp = lg[n] - lse;
            out[t * NW + n] = lp;
            if (n == lab) contrib = -lp;
        }
    }
    #pragma unroll
    for (int off = 32; off; off >>= 1) contrib += __shfl_down(contrib, off);
    __shared__ float red[6];
    if ((t & 63) == 0) red[t >> 6] = contrib;
    __syncthreads();
    if (t == 0) {
        float s = 0.f;
        #pragma unroll
        for (int i = 0; i < 6; ++i) s += red[i];
        out[NQ * NW] = s * (1.f / NQ);
    }
}

extern "C" void kernel_launch(void* const* d_in, const int* in_sizes, int n_in,
                              void* d_out, int out_size, void* d_ws, size_t ws_size,
                              hipStream_t stream) {
    const float* feat  = (const float*)d_in[0];
    const int*   label = (const int*)d_in[1];
    float* out = (float*)d_out;
    float* ws  = (float*)d_ws;
    const float* query = feat + (size_t)NS * CCH * PP;

    k_proto<<<NW * CCH, 128, 0, stream>>>(feat, ws);
    k_qstat<<<NQ, 256, 0, stream>>>(query, ws + OFF_QSQ, ws + OFF_QAVG);
    k_qstat<<<NW, 256, 0, stream>>>(ws + OFF_PROTO, ws + OFF_PSQ, (float*)nullptr);
    k_pconv<<<NW * 16, 256, 0, stream>>>(ws);
    k_pair<<<NPAIR, 256, 0, stream>>>(query, ws);
    k_final<<<1, 384, 0, stream>>>(label, ws, out);
}

// Round 10
// 244.059 us; speedup vs baseline: 2.6918x; 2.6918x over previous
//
#include <hip/hip_runtime.h>
#include <math.h>

#define NW   5
#define PRJ  14
#define CCH  512
#define PP   100
#define NQ   375
#define NS   70
#define NPAIR (NQ*NW)

// ws offsets (floats)
#define OFF_PROTO   0          // 5*512*100 = 256000
#define OFF_PAVG    256000     // 2560
#define OFF_QAVG    258560     // 192000
#define OFF_QSQ     450560     // 37500
#define OFF_PSQ     488060     // 500
#define OFF_LOGITS  488560     // 1875
#define OFF_PF16    490440     // 5 protos * 16 kt * 2048 dwords = 163840

typedef float f32x16 __attribute__((ext_vector_type(16)));
typedef _Float16 f16x2 __attribute__((ext_vector_type(2)));
typedef _Float16 f16x8 __attribute__((ext_vector_type(8)));

__device__ __forceinline__ int SWZ(int n) { return n ^ ((n >> 2) & 7); }

// ---------------- K1: proto = mean over shots; proto_avg ----------------
__global__ void k_proto(const float* __restrict__ feat, float* __restrict__ ws) {
    int nc = blockIdx.x;            // n*512 + c
    int n  = nc >> 9;
    int p  = threadIdx.x;
    float s = 0.f;
    if (p < PP) {
        const float* base = feat + (size_t)((n * PRJ) * CCH) * PP + (size_t)(nc & 511) * PP + p;
        #pragma unroll
        for (int k = 0; k < PRJ; ++k) s += base[(size_t)k * CCH * PP];
        s *= (1.f / PRJ);
        ws[OFF_PROTO + nc * PP + p] = s;
    }
    float v = (p < PP) ? s : 0.f;
    #pragma unroll
    for (int off = 32; off; off >>= 1) v += __shfl_down(v, off);
    __shared__ float red[2];
    if ((threadIdx.x & 63) == 0) red[threadIdx.x >> 6] = v;
    __syncthreads();
    if (threadIdx.x == 0) ws[OFF_PAVG + nc] = (red[0] + red[1]) * (1.f / PP);
}

// ------- K2: per-image transpose-stats: sumsq per node (+ optional avg per ch)
__global__ __launch_bounds__(256) void k_qstat(const float* __restrict__ src,
                                               float* __restrict__ dst_sq,
                                               float* __restrict__ dst_avg) {
    __shared__ __align__(16) float t[6400];
    int b = blockIdx.x, tid = threadIdx.x;
    const float* base = src + (size_t)b * CCH * PP;
    float qsq = 0.f;
    for (int c0 = 0; c0 < CCH; c0 += 64) {
        __syncthreads();
        const float4* g = (const float4*)(base + (size_t)c0 * PP);
        for (int i = tid; i < 1600; i += 256) ((float4*)t)[i] = g[i];
        __syncthreads();
        if (tid < PP) {
            #pragma unroll 8
            for (int c = 0; c < 64; ++c) { float x = t[c * PP + tid]; qsq = fmaf(x, x, qsq); }
        } else if (tid >= 128 && tid < 192) {
            int ch = tid - 128;
            const float4* row = (const float4*)(t + ch * PP);
            float s = 0.f;
            #pragma unroll
            for (int i = 0; i < 25; ++i) { float4 v = row[i]; s += (v.x + v.y) + (v.z + v.w); }
            if (dst_avg) dst_avg[(size_t)b * CCH + c0 + ch] = s * (1.f / PP);
        }
    }
    if (tid < PP) dst_sq[b * PP + tid] = qsq;
}

// ------- K2b: pre-convert protos to SWZ'd f16 images (8KB per kt) -------
// logical col 100 = pavg (phys slot 101), col 101 = ones (phys slot 100)
__global__ __launch_bounds__(256) void k_pconv(float* __restrict__ ws) {
    int b = blockIdx.x;          // n*16 + kt
    int n = b >> 4, kt = b & 15;
    int tid = threadIdx.x;
    int c0 = kt * 32;
    uint* img = (uint*)(ws + OFF_PF16) + (size_t)b * 2048;
    const float* pb = ws + OFF_PROTO + (size_t)n * CCH * PP;
    const float* pavg = ws + OFF_PAVG + n * CCH;
    for (int i = tid; i < 1600; i += 256) {
        int cp = i / 100, col = i - cp * 100;
        float a0 = pb[(size_t)(c0 + 2 * cp) * PP + col];
        float a1 = pb[(size_t)(c0 + 2 * cp + 1) * PP + col];
        uint pk = __builtin_bit_cast(uint, __builtin_amdgcn_cvt_pkrtz(a0, a1));
        img[(((cp >> 2) << 7) | SWZ(col)) * 4 + (cp & 3)] = pk;
    }
    if (tid < 16) {
        int cp = tid;
        float a0 = pavg[c0 + 2 * cp], a1 = pavg[c0 + 2 * cp + 1];
        uint pk = __builtin_bit_cast(uint, __builtin_amdgcn_cvt_pkrtz(a0, a1));
        img[(((cp >> 2) << 7) | 101) * 4 + (cp & 3)] = pk;
    }
    for (int i = tid; i < 448; i += 256) {
        int dw = i & 3; int t2 = i >> 2;
        int s_i = t2 % 28; int k4 = t2 / 28;   // k4 0..3
        int s = 100 + s_i;
        if (s == 101) continue;
        img[(((k4) << 7) | s) * 4 + dw] = (s == 100) ? 0x3C003C00u : 0u;
    }
}

// ------- K3: per-pair: f16 MFMA cost matmul + weights + reg Sinkhorn ----
__global__ __launch_bounds__(256, 4) void k_pair(const float* __restrict__ query,
                                                 float* __restrict__ ws) {
    // SH union: matmul tiles A@0 (8KB), B@8192 (8KB) -> Gibbs Kst (22400B)
    __shared__ __align__(16) char SH[22400];
    __shared__ __align__(16) float uvec[112], vvec[112];   // halves at [0,50) and [56,106)
    __shared__ float wrL[PP], wcL[PP], qnl[PP], pnl[PP], sqv[PP], spv[PP];
    __shared__ float red[8];

    uint* Kst = (uint*)SH;

    // bijective XCD swizzle (nwg=1875 = 8*234+3): same-query pairs land on one XCD
    int p_ = blockIdx.x;
    int xcd = p_ & 7, off_ = p_ >> 3;
    int pair = (xcd < 3) ? (xcd * 235 + off_) : (705 + (xcd - 3) * 234 + off_);

    int m = pair / NW;
    int n = pair - m * NW;
    int tid = threadIdx.x;
    int lane = tid & 63, wid = tid >> 6;
    int lrow = lane & 31, lhi = lane >> 5;

    const float* qb = query + (size_t)m * CCH * PP;
    const float* qavg_g = ws + OFF_QAVG + (size_t)m * CCH;
    const uint* pimg = (const uint*)(ws + OFF_PF16) + (size_t)n * 16 * 2048;

    // A pad slots once: phys slot 100 = ones (logical row 101), 102..127 = 0
    // (phys slot 101 = logical row 100 = qavg, rewritten per kt)
    for (int idx = tid; idx < 112; idx += 256) {
        int s_i = idx % 28; int k4 = idx / 28;
        int s = 100 + s_i;
        if (s == 101) continue;
        uint4 val = (s == 100)
                  ? make_uint4(0x3C003C00u, 0x3C003C00u, 0x3C003C00u, 0x3C003C00u)
                  : make_uint4(0u, 0u, 0u, 0u);
        *(uint4*)&SH[(k4 * 128 + s) * 16] = val;
    }

    f32x16 acc[4];
    #pragma unroll
    for (int tc = 0; tc < 4; ++tc)
        #pragma unroll
        for (int e = 0; e < 16; ++e) acc[tc][e] = 0.f;

    int arow16 = SWZ(32 * wid + lrow) * 16;
    int bcol16[4];
    #pragma unroll
    for (int tc = 0; tc < 4; ++tc) bcol16[tc] = SWZ(32 * tc + lrow) * 16;

    for (int kt = 0; kt < 16; ++kt) {
        int c0 = kt * 32;
        // A: query f32 -> f16 pairs, SWZ slots
        for (int idx = tid; idx < 400; idx += 256) {
            int cp = idx / 25, n4 = idx - cp * 25;
            const float* src = qb + (size_t)(c0 + 2 * cp) * PP + n4 * 4;
            float4 x0 = *(const float4*)src;
            float4 x1 = *(const float4*)(src + PP);
            const float* p0 = (const float*)&x0;
            const float* p1 = (const float*)&x1;
            int basedw = ((cp >> 2) << 7);
            int dwb = (cp & 3) * 4;
            #pragma unroll
            for (int i4 = 0; i4 < 4; ++i4) {
                int node = n4 * 4 + i4;
                uint pk = __builtin_bit_cast(uint, __builtin_amdgcn_cvt_pkrtz(p0[i4], p1[i4]));
                *(uint*)&SH[(basedw + SWZ(node)) * 16 + dwb] = pk;
            }
        }
        // A logical row 100 = qavg (phys slot 101)
        if (tid < 16) {
            int cp = tid;
            uint pk = __builtin_bit_cast(uint,
                __builtin_amdgcn_cvt_pkrtz(qavg_g[c0 + 2 * cp], qavg_g[c0 + 2 * cp + 1]));
            *(uint*)&SH[(((cp >> 2) << 7) + 101) * 16 + (cp & 3) * 4] = pk;
        }
        // B: copy pre-converted f16 proto image (8KB)
        {
            const float4* gB = (const float4*)(pimg + (size_t)kt * 2048);
            float4* sB = (float4*)&SH[8192];
            for (int i = tid; i < 512; i += 256) sB[i] = gB[i];
        }
        __syncthreads();
        __builtin_amdgcn_s_setprio(1);
        #pragma unroll
        for (int s = 0; s < 2; ++s) {
            int kb = (2 * s + lhi) * 2048;
            f16x8 ah = *(const f16x8*)&SH[kb + arow16];
            #pragma unroll
            for (int tc = 0; tc < 4; ++tc) {
                f16x8 bh = *(const f16x8*)&SH[8192 + kb + bcol16[tc]];
                acc[tc] = __builtin_amdgcn_mfma_f32_32x32x16_f16(ah, bh, acc[tc], 0, 0, 0);
            }
        }
        __builtin_amdgcn_s_setprio(0);
        __syncthreads();
    }

    // extract w1 (col 100), sum_q (col 101), w2 (row 100), sum_p (row 101)
    if ((lane & 31) == 4 || (lane & 31) == 5) {
        float* dst = ((lane & 31) == 4) ? wrL : sqv;
        #pragma unroll
        for (int reg = 0; reg < 16; ++reg) {
            int row = 32 * wid + (reg & 3) + 8 * (reg >> 2) + 4 * lhi;
            if (row < PP) dst[row] = acc[3][reg];
        }
    }
    if (wid == 3 && lhi == 1) {
        #pragma unroll
        for (int tc = 0; tc < 4; ++tc) {
            int col = 32 * tc + lrow;
            if (col < PP) { wcL[col] = acc[tc][0]; spv[col] = acc[tc][1]; }
        }
    }
    if (tid < 112) vvec[tid] = 1.f;
    __syncthreads();

    // normalize weights (prescaled by 2^15 to fold the f16 K scaling)
    float v1 = 0.f, v2 = 0.f;
    if (tid < PP) {
        v1 = fmaxf(wrL[tid], 0.f) + 0.00101f;
        v2 = fmaxf(wcL[tid], 0.f) + 0.00101f;
    }
    float s1 = v1, s2 = v2;
    #pragma unroll
    for (int off = 32; off; off >>= 1) { s1 += __shfl_down(s1, off); s2 += __shfl_down(s2, off); }
    if ((tid & 63) == 0) { red[tid >> 6] = s1; red[4 + (tid >> 6)] = s2; }
    __syncthreads();
    float t1 = red[0] + red[1], t2 = red[4] + red[5];
    if (tid < PP) {
        wrL[tid] = v1 * (100.f / t1) * 32768.f;
        wcL[tid] = v2 * (100.f / t2) * 32768.f;
        float sq = sqv[tid], sp = spv[tid];
        qnl[tid] = ws[OFF_QSQ + m * PP + tid] - sq * sq * (1.f / 512.f);
        pnl[tid] = ws[OFF_PSQ + n * PP + tid] - sp * sp * (1.f / 512.f);
    }
    __syncthreads();

    // sqd into acc; block max
    float spc[4], pnc[4];
    #pragma unroll
    for (int tc = 0; tc < 4; ++tc) {
        int col = 32 * tc + lrow;
        bool cv = col < PP;
        spc[tc] = cv ? spv[col] : 0.f;
        pnc[tc] = cv ? pnl[col] : 0.f;
    }
    float mymax = -1e30f;
    #pragma unroll
    for (int reg = 0; reg < 16; ++reg) {
        int row = 32 * wid + (reg & 3) + 8 * (reg >> 2) + 4 * lhi;
        bool rv = row < PP;
        float sqr = rv ? sqv[row] : 0.f;
        float qnr = rv ? qnl[row] : 0.f;
        #pragma unroll
        for (int tc = 0; tc < 4; ++tc) {
            float sqd = qnr + pnc[tc] - 2.f * (acc[tc][reg] - sqr * spc[tc] * (1.f / 512.f));
            acc[tc][reg] = sqd;
            int col = 32 * tc + lrow;
            if (rv && col < PP) mymax = fmaxf(mymax, sqd);
        }
    }
    #pragma unroll
    for (int off = 32; off; off >>= 1) mymax = fmaxf(mymax, __shfl_down(mymax, off));
    __syncthreads();
    if (lane == 0) red[wid] = mymax;
    __syncthreads();
    float scale = fmaxf(fmaxf(red[0], red[1]), fmaxf(red[2], red[3])) + 1e-6f;
    float k2 = (1.f / scale) * (20.f * 1.44269504088896f);

    // Gibbs K' = 2^(15 - sqd*k2) f16-pair rows -> Kst (tiles are dead)
    #pragma unroll
    for (int tc = 0; tc < 4; ++tc) {
        float kv[16];
        #pragma unroll
        for (int reg = 0; reg < 16; ++reg) kv[reg] = exp2f(fmaf(-acc[tc][reg], k2, 15.f));
        int col = 32 * tc + lrow;
        #pragma unroll
        for (int reg = 0; reg < 16; ++reg) {
            float pv = __shfl_xor(kv[reg], 1);
            int row = 32 * wid + (reg & 3) + 8 * (reg >> 2) + 4 * lhi;
            if (!(lane & 1) && row < PP && col < PP) {
                int j = col >> 1;
                int dw = (j < 25) ? j : (j + 3);     // halves at +0 / +28
                uint pk = __builtin_bit_cast(uint, __builtin_amdgcn_cvt_pkrtz(kv[reg], pv));
                Kst[row * 56 + dw] = pk;
            }
        }
    }
    __syncthreads();

    // load K row-half and gathered col-half into registers
    int r_ = tid >> 1, hf = tid & 1;
    bool sact = tid < 200;
    int widx = r_ + (r_ >= 50 ? 6 : 0);
    uint Kr[25], KTr[25];
    float wr_own = 0.f, wc_own = 0.f;
    if (sact) {
        const uint* rp = Kst + r_ * 56 + 28 * hf;
        #pragma unroll
        for (int q = 0; q < 25; ++q) Kr[q] = rp[q];
        int j = r_ >> 1;
        int dwc = (j < 25) ? j : (j + 3);
        int sh = (r_ & 1) * 16;
        const uint* cp0 = Kst + (50 * hf) * 56 + dwc;
        #pragma unroll
        for (int q = 0; q < 25; ++q) {
            uint d0 = cp0[(2 * q) * 56];
            uint d1 = cp0[(2 * q + 1) * 56];
            KTr[q] = ((d0 >> sh) & 0xFFFFu) | (((d1 >> sh) & 0xFFFFu) << 16);
        }
        wr_own = wrL[r_];
        wc_own = wcL[r_];
    }
    __syncthreads();

    // linear Sinkhorn, K in registers; only u/v broadcasts touch LDS
    for (int it = 0; it < 50; ++it) {
        if (sact) {
            const float* vp = vvec + hf * 56;
            float sA = 0.f, sB = 0.f;
            #pragma unroll
            for (int q = 0; q < 25; ++q) {
                f16x2 h = __builtin_bit_cast(f16x2, Kr[q]);
                sA = fmaf((float)h[0], vp[2 * q], sA);
                sB = fmaf((float)h[1], vp[2 * q + 1], sB);
            }
            float s = sA + sB;
            s += __shfl_xor(s, 1);
            if (!hf) uvec[widx] = wr_own * __builtin_amdgcn_rcpf(s);
        }
        __syncthreads();
        if (sact) {
            const float* up = uvec + hf * 56;
            float sA = 0.f, sB = 0.f;
            #pragma unroll
            for (int q = 0; q < 25; ++q) {
                f16x2 h = __builtin_bit_cast(f16x2, KTr[q]);
                sA = fmaf((float)h[0], up[2 * q], sA);
                sB = fmaf((float)h[1], up[2 * q + 1], sB);
            }
            float s = sA + sB;
            s += __shfl_xor(s, 1);
            if (!hf) vvec[widx] = wc_own * __builtin_amdgcn_rcpf(s);
        }
        __syncthreads();
    }

    // epilogue: sqd recovered from stored K'
    float lsum = 0.f;
    if (sact) {
        float ur = uvec[widx];
        const float* vp = vvec + hf * 56;
        float rk2 = scale * (1.f / (20.f * 1.44269504088896f));
        #pragma unroll
        for (int q = 0; q < 25; ++q) {
            f16x2 h = __builtin_bit_cast(f16x2, Kr[q]);
            float k0 = (float)h[0], k1 = (float)h[1];
            float sq0 = (15.f - __log2f(k0)) * rk2;
            float sq1 = (15.f - __log2f(k1)) * rk2;
            lsum = fmaf((1.f - sq0) * k0, vp[2 * q], lsum);
            lsum = fmaf((1.f - sq1) * k1, vp[2 * q + 1], lsum);
        }
        lsum *= ur;
    }
    #pragma unroll
    for (int off = 32; off; off >>= 1) lsum += __shfl_down(lsum, off);
    if (lane == 0) red[wid] = lsum;
    __syncthreads();
    if (tid == 0)
        ws[OFF_LOGITS + pair] = ((red[0] + red[1]) + (red[2] + red[3])) * (0.125f / 32768.f);
}

// ---------------- K4: log-softmax + loss --------------------------------
__global__ void k_final(const int* __restrict__ label, const float* __restrict__ ws,
                        float* __restrict__ out) {
    int t = threadIdx.x;   // 384 threads
    float contrib = 0.f;
    if (t < NQ) {
        float lg[NW];
        #pragma unroll
        for (int n = 0; n < NW; ++n) lg[n] = ws[OFF_LOGITS + t * NW + n];
        float mx = lg[0];
        #pragma unroll
        for (int n = 1; n < NW; ++n) mx = fmaxf(mx, lg[n]);
        float s = 0.f;
        #pragma unroll
        for (int n = 0; n < NW; ++n) s += expf(lg[n] - mx);
        float lse = mx + logf(s);
        int lab = label[t];
        #pragma unroll
        for (int n = 0; n < NW; ++n) {
            float lp = lg[n] - lse;
            out[t * NW + n] = lp;
            if (n == lab) contrib = -lp;
        }
    }
    #pragma unroll
    for (int off = 32; off; off >>= 1) contrib += __shfl_down(contrib, off);
    __shared__ float red[6];
    if ((t & 63) == 0) red[t >> 6] = contrib;
    __syncthreads();
    if (t == 0) {
        float s = 0.f;
        #pragma unroll
        for (int i = 0; i < 6; ++i) s += red[i];
        out[NQ * NW] = s * (1.f / NQ);
    }
}

extern "C" void kernel_launch(void* const* d_in, const int* in_sizes, int n_in,
                              void* d_out, int out_size, void* d_ws, size_t ws_size,
                              hipStream_t stream) {
    const float* feat  = (const float*)d_in[0];
    const int*   label = (const int*)d_in[1];
    float* out = (float*)d_out;
    float* ws  = (float*)d_ws;
    const float* query = feat + (size_t)NS * CCH * PP;

    k_proto<<<NW * CCH, 128, 0, stream>>>(feat, ws);
    k_qstat<<<NQ, 256, 0, stream>>>(query, ws + OFF_QSQ, ws + OFF_QAVG);
    k_qstat<<<NW, 256, 0, stream>>>(ws + OFF_PROTO, ws + OFF_PSQ, (float*)nullptr);
    k_pconv<<<NW * 16, 256, 0, stream>>>(ws);
    k_pair<<<NPAIR, 256, 0, stream>>>(query, ws);
    k_final<<<1, 384, 0, stream>>>(label, ws, out);
}